// Round 2
// baseline (529.079 us; speedup 1.0000x reference)
//
#include <hip/hip_runtime.h>
#include <hip/hip_bf16.h>
#include <stdint.h>

#define K1 1.4426950408889634f
#define K2 2.8853900817779268f

typedef float f4 __attribute__((ext_vector_type(4)));
typedef float f2 __attribute__((ext_vector_type(2)));
typedef short s8v __attribute__((ext_vector_type(8)));
typedef unsigned int u32;
typedef unsigned short u16;

// workspace offsets (bytes)
#define WS_WCAT  0        // u16[512*192] permuted+concat gate weights (bf16)
#define WS_WG    196608   // u16[64*64]   ln1-folded emb weights, k-padded (bf16)
#define WS_TE    204800   // f32[64]
#define WS_SE    205056   // f32[64]
#define WS_PWLN  205312   // f32[256]  pos_W * ln2_w
#define WS_SPW   206336   // f32[2]
#define WS_PBE   206344   // f32[2]
#define WS_BC    206352   // f32[512]  permuted b_ih+b_hh
#define WS_FLAGS 208400   // int[32] per-step done counters

__device__ __forceinline__ u16 f2bf(float x) {
    u32 u = __builtin_bit_cast(u32, x);
    u32 r = (u + 0x7FFFu + ((u >> 16) & 1u)) >> 16;
    return (u16)r;
}
__device__ __forceinline__ float bf2f(u16 h) {
    u32 u = ((u32)h) << 16;
    return __builtin_bit_cast(float, u);
}

__global__ void prep_kernel(const float* __restrict__ ln1w, const float* __restrict__ ln1b,
                            const float* __restrict__ embW, const float* __restrict__ embB,
                            const float* __restrict__ Wih, const float* __restrict__ Whh,
                            const float* __restrict__ bih, const float* __restrict__ bhh,
                            const float* __restrict__ ln2w, const float* __restrict__ ln2b,
                            const float* __restrict__ posW, const float* __restrict__ posB,
                            char* __restrict__ ws) {
    int tid = threadIdx.x;
    u16* wcat = (u16*)(ws + WS_WCAT);
    u16* wg   = (u16*)(ws + WS_WG);
    float* te = (float*)(ws + WS_TE);
    float* se = (float*)(ws + WS_SE);
    float* pwln = (float*)(ws + WS_PWLN);
    float* spw  = (float*)(ws + WS_SPW);
    float* pbe  = (float*)(ws + WS_PBE);
    float* bc   = (float*)(ws + WS_BC);
    int* flags  = (int*)(ws + WS_FLAGS);

    // gate weights: row n' = 128w + 32g + 16jt + c  <->  orig row g*128 + (32w+16jt+c)
    for (int idx = tid; idx < 512 * 192; idx += 256) {
        int np = idx / 192, k = idx % 192;
        int w = np >> 7, r = np & 127, nt = r >> 4, c = r & 15;
        int g = nt >> 1, jt = nt & 1;
        int n0 = (g << 7) | (w << 5) | (jt << 4) | c;
        float v = (k < 64) ? Wih[n0 * 64 + k] : Whh[n0 * 128 + (k - 64)];
        wcat[idx] = f2bf(v);
    }
    for (int idx = tid; idx < 64 * 64; idx += 256) {
        int e = idx >> 6, k = idx & 63;
        float v = (k < 40) ? embW[e * 40 + k] * ln1w[k] : 0.0f;
        wg[idx] = f2bf(v);
    }
    if (tid < 64) {
        int e = tid;
        float t = embB[e], s = 0.f;
        for (int k = 0; k < 40; ++k) {
            t += embW[e * 40 + k] * ln1b[k];
            s += bf2f(f2bf(embW[e * 40 + k] * ln1w[k]));
        }
        te[e] = t; se[e] = s;
    }
    {
        int d = tid >> 7, j = tid & 127;
        pwln[tid] = posW[d * 128 + j] * ln2w[j];
    }
    if (tid < 2) {
        float s = 0.f, p = posB[tid];
        for (int j = 0; j < 128; ++j) {
            s += posW[tid * 128 + j] * ln2w[j];
            p += posW[tid * 128 + j] * ln2b[j];
        }
        spw[tid] = s; pbe[tid] = p;
    }
    for (int idx = tid; idx < 512; idx += 256) {
        int w = idx >> 7, r = idx & 127, nt = r >> 4, c = r & 15;
        int g = nt >> 1, jt = nt & 1;
        int n0 = (g << 7) | (w << 5) | (jt << 4) | c;
        bc[idx] = bih[n0] + bhh[n0];
    }
    if (tid < 32) flags[tid] = 0;   // per-step done counters
}

__global__ __launch_bounds__(256, 1)
void lstm_kernel(const float* __restrict__ traj_rel,
                 const float* __restrict__ h0, const float* __restrict__ c0,
                 float* __restrict__ dout, char* __restrict__ ws) {
    // LDS: chunk-major layouts -> 16-lane groups read 256B contiguous (no bank conflicts)
    __shared__ __align__(16) u16 s_whh[16 * 512 * 8];   // 131072 B: [k2chunk][n'][8]
    __shared__ __align__(16) u16 s_xh[24 * 32 * 8];     // 12288 B: [kchunk][agent][8] (x|h bf16)
    __shared__ __align__(16) u16 s_win[8 * 32 * 8];     // 4096 B : [kchunk][agent][8]
    __shared__ __align__(16) float s_red[4][32][4];     // 2048 B : per-wave ln2 partials
    __shared__ __align__(16) f2 s_wp[320];              // 2560 B : window sum/sumsq partials
    __shared__ float s_mr[32][2];                       // 256 B  : ln1 mean, rstd

    const int tid = threadIdx.x;
    const int bk = blockIdx.x;
    const int lane = tid & 63;
    const int wvi = tid >> 6;        // wave 0..3 -> gate slice [128*wvi, +128), j slice [32*wvi,+32)
    const int cx = lane & 15;
    const int hi4 = (lane >> 4) * 4;

    const u16* wcat = (const u16*)(ws + WS_WCAT);
    const u16* wg = (const u16*)(ws + WS_WG);
    int* flags = (int*)(ws + WS_FLAGS);

    // ---------------- init: resident weights ----------------
    s8v wih[8][2];
#pragma unroll
    for (int nt = 0; nt < 8; ++nt)
#pragma unroll
        for (int kc = 0; kc < 2; ++kc) {
            int rowp = 128 * wvi + 16 * nt + cx;
            wih[nt][kc] = *(const s8v*)(wcat + rowp * 192 + kc * 32 + (lane >> 4) * 8);
        }
    s8v wgf[2];
#pragma unroll
    for (int kc = 0; kc < 2; ++kc)
        wgf[kc] = *(const s8v*)(wg + (16 * wvi + cx) * 64 + kc * 32 + (lane >> 4) * 8);

    float se_l = ((const float*)(ws + WS_SE))[16 * wvi + cx];
    float te_l = ((const float*)(ws + WS_TE))[16 * wvi + cx];
    float bias[8];
#pragma unroll
    for (int nt = 0; nt < 8; ++nt)
        bias[nt] = ((const float*)(ws + WS_BC))[128 * wvi + 16 * nt + cx];
    float pwl[2][2];
#pragma unroll
    for (int d = 0; d < 2; ++d)
#pragma unroll
        for (int jt = 0; jt < 2; ++jt)
            pwl[d][jt] = ((const float*)(ws + WS_PWLN))[d * 128 + 32 * wvi + 16 * jt + cx];
    float spw0 = ((const float*)(ws + WS_SPW))[0];
    float spw1 = ((const float*)(ws + WS_SPW))[1];
    float pbe0 = ((const float*)(ws + WS_PBE))[0];
    float pbe1 = ((const float*)(ws + WS_PBE))[1];

    // stage W_hh -> LDS (chunk-major)
    for (int idx = tid; idx < 16 * 512; idx += 256) {
        const u16* src = wcat + (idx & 511) * 192 + 64 + (idx >> 9) * 8;
        *(s8v*)(s_whh + idx * 8) = *(const s8v*)src;
    }
    // zero window pad chunks (k = 40..63)
    if (tid < 96) {
        int ch = 5 + tid / 32, a = tid & 31;
        s8v z = {0, 0, 0, 0, 0, 0, 0, 0};
        *(s8v*)(s_win + (ch * 32 + a) * 8) = z;
    }
    // h0 -> xh cols 64..191 (bf16)
    {
        int a = tid & 31, q = tid >> 5;
        const float* hp = h0 + (bk * 32 + a) * 128 + q * 16;
        u16 hb[16];
#pragma unroll
        for (int u = 0; u < 16; ++u) hb[u] = f2bf(hp[u]);
#pragma unroll
        for (int half = 0; half < 2; ++half) {
            s8v v;
#pragma unroll
            for (int u = 0; u < 8; ++u) v[u] = (short)hb[half * 8 + u];
            int ch = 8 + 2 * q + half;
            *(s8v*)(s_xh + (ch * 32 + a) * 8) = v;
        }
    }
    // c0 -> registers (D-fragment layout)
    float creg[2][2][4];
#pragma unroll
    for (int mt = 0; mt < 2; ++mt)
#pragma unroll
        for (int jt = 0; jt < 2; ++jt)
#pragma unroll
            for (int rg = 0; rg < 4; ++rg) {
                int a = 16 * mt + hi4 + rg;
                int j = 32 * wvi + 16 * jt + cx;
                creg[mt][jt][rg] = c0[(bk * 32 + a) * 128 + j];
            }
    __syncthreads();

    // ---------------- 30-step recurrence ----------------
#pragma unroll 1
    for (int t = 0; t < 30; ++t) {
        // wait for producers: single-address per-step done counter.
        // need stream elements < Wend; preds of step s fully available once
        // done[s]==256. s_max = (Wend-1-327680)>>14 <= t-1 always (no deadlock).
        if (tid == 0) {
            int Wend = 16384 * t + 1280 * bk + 1280;
            if (Wend > 327680) {
                int smax = (Wend - 327681) >> 14;
                while (__hip_atomic_load(&flags[smax], __ATOMIC_RELAXED, __HIP_MEMORY_SCOPE_AGENT) < 256)
                    __builtin_amdgcn_s_sleep(1);
                (void)__hip_atomic_load(&flags[smax], __ATOMIC_ACQUIRE, __HIP_MEMORY_SCOPE_AGENT);
            }
        }
        __syncthreads();  // B1

        // stage window (stream = traj_rel ++ dout), f32 stats partials
        int W0 = 16384 * t + 1280 * bk;
        {
            int p = W0 + 4 * tid;
            const float* src = (p < 327680) ? (traj_rel + p) : (dout + (p - 327680));
            f4 v = *(const f4*)src;
            int a = tid / 10, kq = (tid % 10) * 4;
            u32 lo = (u32)f2bf(v[0]) | ((u32)f2bf(v[1]) << 16);
            u32 hh = (u32)f2bf(v[2]) | ((u32)f2bf(v[3]) << 16);
            u32* dst = (u32*)(s_win + ((kq >> 3) * 32 + a) * 8 + (kq & 7));
            dst[0] = lo; dst[1] = hh;
            s_wp[tid] = f2{v[0] + v[1] + v[2] + v[3],
                           v[0] * v[0] + v[1] * v[1] + v[2] * v[2] + v[3] * v[3]};
        }
        if (tid < 64) {
            int idx1 = tid + 256;
            int p = W0 + 4 * idx1;
            const float* src = (p < 327680) ? (traj_rel + p) : (dout + (p - 327680));
            f4 v = *(const f4*)src;
            int a = idx1 / 10, kq = (idx1 % 10) * 4;
            u32 lo = (u32)f2bf(v[0]) | ((u32)f2bf(v[1]) << 16);
            u32 hh = (u32)f2bf(v[2]) | ((u32)f2bf(v[3]) << 16);
            u32* dst = (u32*)(s_win + ((kq >> 3) * 32 + a) * 8 + (kq & 7));
            dst[0] = lo; dst[1] = hh;
            s_wp[idx1] = f2{v[0] + v[1] + v[2] + v[3],
                            v[0] * v[0] + v[1] * v[1] + v[2] * v[2] + v[3] * v[3]};
        }
        __syncthreads();  // B2: window + partials ready

        // ln1 stats (deterministic serial sum per agent)
        if (tid < 32) {
            float s = 0.f, s2 = 0.f;
#pragma unroll
            for (int u = 0; u < 10; ++u) {
                f2 p = s_wp[tid * 10 + u];
                s += p[0]; s2 += p[1];
            }
            float m = s * (1.0f / 40.0f);
            float var = s2 * (1.0f / 40.0f) - m * m;
            s_mr[tid][0] = m;
            s_mr[tid][1] = __builtin_amdgcn_rsqf(var + 1e-5f);
        }
        // embedding MFMA on raw bf16 window
        f4 accE[2];
        accE[0] = f4{0.f, 0.f, 0.f, 0.f};
        accE[1] = f4{0.f, 0.f, 0.f, 0.f};
#pragma unroll
        for (int kc = 0; kc < 2; ++kc)
#pragma unroll
            for (int mt = 0; mt < 2; ++mt) {
                s8v a = *(const s8v*)(s_win + ((kc * 4 + (lane >> 4)) * 32 + 16 * mt + cx) * 8);
                accE[mt] = __builtin_amdgcn_mfma_f32_16x16x32_bf16(a, wgf[kc], accE[mt], 0, 0, 0);
            }
        __syncthreads();  // B3: s_mr ready

        // emb epilogue: ln1 fold + leaky_relu -> xh (bf16)
        {
            int e = 16 * wvi + cx;
#pragma unroll
            for (int mt = 0; mt < 2; ++mt)
#pragma unroll
                for (int rg = 0; rg < 4; ++rg) {
                    int a = 16 * mt + hi4 + rg;
                    float m = s_mr[a][0], r = s_mr[a][1];
                    float x = r * (accE[mt][rg] - m * se_l) + te_l;
                    x = fmaxf(x, 0.f) + 0.01f * fminf(x, 0.f);
                    s_xh[((e >> 3) * 32 + a) * 8 + (e & 7)] = f2bf(x);
                }
        }
        __syncthreads();  // B4: xh (x new, h from prev step) complete

        // gates GEMM [32 x 192] x [192 x 512]
        f4 acc[2][8];
#pragma unroll
        for (int mt = 0; mt < 2; ++mt)
#pragma unroll
            for (int nt = 0; nt < 8; ++nt)
                acc[mt][nt] = f4{bias[nt], bias[nt], bias[nt], bias[nt]};
#pragma unroll
        for (int kc = 0; kc < 6; ++kc) {
            s8v a0 = *(const s8v*)(s_xh + ((kc * 4 + (lane >> 4)) * 32 + cx) * 8);
            s8v a1 = *(const s8v*)(s_xh + ((kc * 4 + (lane >> 4)) * 32 + 16 + cx) * 8);
#pragma unroll
            for (int nt = 0; nt < 8; ++nt) {
                s8v b;
                if (kc < 2) b = wih[nt][kc];
                else b = *(const s8v*)(s_whh + (((kc - 2) * 4 + (lane >> 4)) * 512 + 128 * wvi + 16 * nt + cx) * 8);
                acc[0][nt] = __builtin_amdgcn_mfma_f32_16x16x32_bf16(a0, b, acc[0][nt], 0, 0, 0);
                acc[1][nt] = __builtin_amdgcn_mfma_f32_16x16x32_bf16(a1, b, acc[1][nt], 0, 0, 0);
            }
        }
        __syncthreads();  // B5: all old-h reads done before overwrite

        // LSTM pointwise (all in-register; gate rows pre-permuted)
        float sh[2][4], sh2[2][4], sp0[2][4], sp1[2][4];
#pragma unroll
        for (int mt = 0; mt < 2; ++mt)
#pragma unroll
            for (int rg = 0; rg < 4; ++rg) {
                sh[mt][rg] = 0.f; sh2[mt][rg] = 0.f; sp0[mt][rg] = 0.f; sp1[mt][rg] = 0.f;
            }
#pragma unroll
        for (int mt = 0; mt < 2; ++mt)
#pragma unroll
            for (int jt = 0; jt < 2; ++jt)
#pragma unroll
                for (int rg = 0; rg < 4; ++rg) {
                    float iv = acc[mt][jt][rg];
                    float fv = acc[mt][2 + jt][rg];
                    float gv = acc[mt][4 + jt][rg];
                    float ov = acc[mt][6 + jt][rg];
                    float si = __builtin_amdgcn_rcpf(1.f + __builtin_amdgcn_exp2f(-K1 * iv));
                    float sf = __builtin_amdgcn_rcpf(1.f + __builtin_amdgcn_exp2f(-K1 * fv));
                    float so = __builtin_amdgcn_rcpf(1.f + __builtin_amdgcn_exp2f(-K1 * ov));
                    float tg = 1.f - 2.f * __builtin_amdgcn_rcpf(1.f + __builtin_amdgcn_exp2f(K2 * gv));
                    float cn = sf * creg[mt][jt][rg] + si * tg;
                    creg[mt][jt][rg] = cn;
                    float tc = 1.f - 2.f * __builtin_amdgcn_rcpf(1.f + __builtin_amdgcn_exp2f(K2 * cn));
                    float hn = so * tc;
                    sh[mt][rg] += hn;
                    sh2[mt][rg] += hn * hn;
                    sp0[mt][rg] += hn * pwl[0][jt];
                    sp1[mt][rg] += hn * pwl[1][jt];
                    int k = 64 + 32 * wvi + 16 * jt + cx;
                    int a = 16 * mt + hi4 + rg;
                    s_xh[((k >> 3) * 32 + a) * 8 + (k & 7)] = f2bf(hn);
                }
        // reduce ln2 partial sums across the 16-lane column group
#pragma unroll
        for (int mt = 0; mt < 2; ++mt)
#pragma unroll
            for (int rg = 0; rg < 4; ++rg) {
                float a0 = sh[mt][rg], a1 = sh2[mt][rg], a2 = sp0[mt][rg], a3 = sp1[mt][rg];
#pragma unroll
                for (int m = 1; m < 16; m <<= 1) {
                    a0 += __shfl_xor(a0, m, 64);
                    a1 += __shfl_xor(a1, m, 64);
                    a2 += __shfl_xor(a2, m, 64);
                    a3 += __shfl_xor(a3, m, 64);
                }
                if (cx == 0) {
                    int a = 16 * mt + hi4 + rg;
                    s_red[wvi][a][0] = a0; s_red[wvi][a][1] = a1;
                    s_red[wvi][a][2] = a2; s_red[wvi][a][3] = a3;
                }
            }
        __syncthreads();  // B6: partials ready (and new h written)

        // combine: ln2 fold -> rel_pos -> d_out (the shared stream)
        if (tid < 64) {
            int a = tid & 31, d = tid >> 5;
            f4 s0 = *(f4*)&s_red[0][a][0];
            f4 s1 = *(f4*)&s_red[1][a][0];
            f4 s2 = *(f4*)&s_red[2][a][0];
            f4 s3 = *(f4*)&s_red[3][a][0];
            f4 sum = s0 + s1 + s2 + s3;
            float m = sum[0] * (1.f / 128.f);
            float var = sum[1] * (1.f / 128.f) - m * m;
            float r = __builtin_amdgcn_rsqf(var + 1e-5f);
            float P = (d == 0) ? sum[2] : sum[3];
            float sp = (d == 0) ? spw0 : spw1;
            float pb = (d == 0) ? pbe0 : pbe1;
            dout[(t * 8192 + bk * 32 + a) * 2 + d] = r * (P - m * sp) + pb;
        }
        __syncthreads();  // B7: pred stores drained (waitcnt before barrier)
        if (tid == 0)
            __hip_atomic_fetch_add(&flags[t], 1, __ATOMIC_RELEASE, __HIP_MEMORY_SCOPE_AGENT);
    }
}

extern "C" void kernel_launch(void* const* d_in, const int* in_sizes, int n_in,
                              void* d_out, int out_size, void* d_ws, size_t ws_size,
                              hipStream_t stream) {
    (void)in_sizes; (void)n_in; (void)out_size; (void)ws_size;
    const float* traj_rel = (const float*)d_in[1];
    const float* h0 = (const float*)d_in[2];
    const float* c0 = (const float*)d_in[3];
    const float* ln1w = (const float*)d_in[4];
    const float* ln1b = (const float*)d_in[5];
    const float* embW = (const float*)d_in[6];
    const float* embB = (const float*)d_in[7];
    const float* Wih = (const float*)d_in[8];
    const float* Whh = (const float*)d_in[9];
    const float* bih = (const float*)d_in[10];
    const float* bhh = (const float*)d_in[11];
    const float* ln2w = (const float*)d_in[12];
    const float* ln2b = (const float*)d_in[13];
    const float* posW = (const float*)d_in[14];
    const float* posB = (const float*)d_in[15];
    char* ws = (char*)d_ws;

    hipLaunchKernelGGL(prep_kernel, dim3(1), dim3(256), 0, stream,
                       ln1w, ln1b, embW, embB, Wih, Whh, bih, bhh, ln2w, ln2b, posW, posB, ws);
    hipLaunchKernelGGL(lstm_kernel, dim3(256), dim3(256), 0, stream,
                       traj_rel, h0, c0, (float*)d_out, ws);
}

// Round 3
// 330.586 us; speedup vs baseline: 1.6004x; 1.6004x over previous
//
#include <hip/hip_runtime.h>
#include <hip/hip_bf16.h>
#include <stdint.h>

#define K1 1.4426950408889634f
#define K2 2.8853900817779268f

typedef float f4 __attribute__((ext_vector_type(4)));
typedef float f2 __attribute__((ext_vector_type(2)));
typedef short s8v __attribute__((ext_vector_type(8)));
typedef unsigned int u32;
typedef unsigned short u16;

// workspace offsets (bytes)
#define WS_WCAT  0        // u16[512*192] permuted+concat gate weights (bf16)
#define WS_WG    196608   // u16[64*64]   ln1-folded emb weights, k-padded (bf16)
#define WS_TE    204800   // f32[64]
#define WS_SE    205056   // f32[64]
#define WS_PWLN  205312   // f32[256]  pos_W * ln2_w
#define WS_SPW   206336   // f32[2]
#define WS_PBE   206344   // f32[2]
#define WS_BC    206352   // f32[512]  permuted b_ih+b_hh
#define WS_FLAGS 208400   // int[256] per-block step progress

__device__ __forceinline__ u16 f2bf(float x) {
    u32 u = __builtin_bit_cast(u32, x);
    u32 r = (u + 0x7FFFu + ((u >> 16) & 1u)) >> 16;
    return (u16)r;
}
__device__ __forceinline__ float bf2f(u16 h) {
    u32 u = ((u32)h) << 16;
    return __builtin_bit_cast(float, u);
}

__global__ void prep_kernel(const float* __restrict__ ln1w, const float* __restrict__ ln1b,
                            const float* __restrict__ embW, const float* __restrict__ embB,
                            const float* __restrict__ Wih, const float* __restrict__ Whh,
                            const float* __restrict__ bih, const float* __restrict__ bhh,
                            const float* __restrict__ ln2w, const float* __restrict__ ln2b,
                            const float* __restrict__ posW, const float* __restrict__ posB,
                            char* __restrict__ ws) {
    int tid = threadIdx.x;
    u16* wcat = (u16*)(ws + WS_WCAT);
    u16* wg   = (u16*)(ws + WS_WG);
    float* te = (float*)(ws + WS_TE);
    float* se = (float*)(ws + WS_SE);
    float* pwln = (float*)(ws + WS_PWLN);
    float* spw  = (float*)(ws + WS_SPW);
    float* pbe  = (float*)(ws + WS_PBE);
    float* bc   = (float*)(ws + WS_BC);
    int* flags  = (int*)(ws + WS_FLAGS);

    // gate weights: row n' = 128w + 32g + 16jt + c  <->  orig row g*128 + (32w+16jt+c)
    for (int idx = tid; idx < 512 * 192; idx += 256) {
        int np = idx / 192, k = idx % 192;
        int w = np >> 7, r = np & 127, nt = r >> 4, c = r & 15;
        int g = nt >> 1, jt = nt & 1;
        int n0 = (g << 7) | (w << 5) | (jt << 4) | c;
        float v = (k < 64) ? Wih[n0 * 64 + k] : Whh[n0 * 128 + (k - 64)];
        wcat[idx] = f2bf(v);
    }
    for (int idx = tid; idx < 64 * 64; idx += 256) {
        int e = idx >> 6, k = idx & 63;
        float v = (k < 40) ? embW[e * 40 + k] * ln1w[k] : 0.0f;
        wg[idx] = f2bf(v);
    }
    if (tid < 64) {
        int e = tid;
        float t = embB[e], s = 0.f;
        for (int k = 0; k < 40; ++k) {
            t += embW[e * 40 + k] * ln1b[k];
            s += bf2f(f2bf(embW[e * 40 + k] * ln1w[k]));
        }
        te[e] = t; se[e] = s;
    }
    {
        int d = tid >> 7, j = tid & 127;
        pwln[tid] = posW[d * 128 + j] * ln2w[j];
    }
    if (tid < 2) {
        float s = 0.f, p = posB[tid];
        for (int j = 0; j < 128; ++j) {
            s += posW[tid * 128 + j] * ln2w[j];
            p += posW[tid * 128 + j] * ln2b[j];
        }
        spw[tid] = s; pbe[tid] = p;
    }
    for (int idx = tid; idx < 512; idx += 256) {
        int w = idx >> 7, r = idx & 127, nt = r >> 4, c = r & 15;
        int g = nt >> 1, jt = nt & 1;
        int n0 = (g << 7) | (w << 5) | (jt << 4) | c;
        bc[idx] = bih[n0] + bhh[n0];
    }
    flags[tid] = 0;   // per-block progress
}

__global__ __launch_bounds__(256, 1)
void lstm_kernel(const float* __restrict__ traj_rel,
                 const float* __restrict__ h0, const float* __restrict__ c0,
                 float* __restrict__ dout, char* __restrict__ ws) {
    // LDS: chunk-major layouts -> 16-lane groups read 256B contiguous (no bank conflicts)
    __shared__ __align__(16) u16 s_whh[16 * 512 * 8];   // 131072 B: [k2chunk][n'][8]
    __shared__ __align__(16) u16 s_xh[24 * 32 * 8];     // 12288 B: [kchunk][agent][8] (x|h bf16)
    __shared__ __align__(16) u16 s_win[8 * 32 * 8];     // 4096 B : [kchunk][agent][8]
    __shared__ __align__(16) float s_red[4][32][4];     // 2048 B : per-wave ln2 partials
    __shared__ __align__(16) f2 s_wp[320];              // 2560 B : window sum/sumsq partials
    __shared__ float s_mr[32][2];                       // 256 B  : ln1 mean, rstd

    const int tid = threadIdx.x;
    const int bk = blockIdx.x;
    const int lane = tid & 63;
    const int wvi = tid >> 6;        // wave 0..3 -> gate slice [128*wvi, +128), j slice [32*wvi,+32)
    const int cx = lane & 15;
    const int hi4 = (lane >> 4) * 4;

    const u16* wcat = (const u16*)(ws + WS_WCAT);
    const u16* wg = (const u16*)(ws + WS_WG);
    int* flags = (int*)(ws + WS_FLAGS);

    // ---------------- init: resident weights ----------------
    s8v wih[8][2];
#pragma unroll
    for (int nt = 0; nt < 8; ++nt)
#pragma unroll
        for (int kc = 0; kc < 2; ++kc) {
            int rowp = 128 * wvi + 16 * nt + cx;
            wih[nt][kc] = *(const s8v*)(wcat + rowp * 192 + kc * 32 + (lane >> 4) * 8);
        }
    s8v wgf[2];
#pragma unroll
    for (int kc = 0; kc < 2; ++kc)
        wgf[kc] = *(const s8v*)(wg + (16 * wvi + cx) * 64 + kc * 32 + (lane >> 4) * 8);

    float se_l = ((const float*)(ws + WS_SE))[16 * wvi + cx];
    float te_l = ((const float*)(ws + WS_TE))[16 * wvi + cx];
    float bias[8];
#pragma unroll
    for (int nt = 0; nt < 8; ++nt)
        bias[nt] = ((const float*)(ws + WS_BC))[128 * wvi + 16 * nt + cx];
    float pwl[2][2];
#pragma unroll
    for (int d = 0; d < 2; ++d)
#pragma unroll
        for (int jt = 0; jt < 2; ++jt)
            pwl[d][jt] = ((const float*)(ws + WS_PWLN))[d * 128 + 32 * wvi + 16 * jt + cx];
    float spw0 = ((const float*)(ws + WS_SPW))[0];
    float spw1 = ((const float*)(ws + WS_SPW))[1];
    float pbe0 = ((const float*)(ws + WS_PBE))[0];
    float pbe1 = ((const float*)(ws + WS_PBE))[1];

    // stage W_hh -> LDS (chunk-major)
    for (int idx = tid; idx < 16 * 512; idx += 256) {
        const u16* src = wcat + (idx & 511) * 192 + 64 + (idx >> 9) * 8;
        *(s8v*)(s_whh + idx * 8) = *(const s8v*)src;
    }
    // zero window pad chunks (k = 40..63)
    if (tid < 96) {
        int ch = 5 + tid / 32, a = tid & 31;
        s8v z = {0, 0, 0, 0, 0, 0, 0, 0};
        *(s8v*)(s_win + (ch * 32 + a) * 8) = z;
    }
    // h0 -> xh cols 64..191 (bf16)
    {
        int a = tid & 31, q = tid >> 5;
        const float* hp = h0 + (bk * 32 + a) * 128 + q * 16;
        u16 hb[16];
#pragma unroll
        for (int u = 0; u < 16; ++u) hb[u] = f2bf(hp[u]);
#pragma unroll
        for (int half = 0; half < 2; ++half) {
            s8v v;
#pragma unroll
            for (int u = 0; u < 8; ++u) v[u] = (short)hb[half * 8 + u];
            int ch = 8 + 2 * q + half;
            *(s8v*)(s_xh + (ch * 32 + a) * 8) = v;
        }
    }
    // c0 -> registers (D-fragment layout)
    float creg[2][2][4];
#pragma unroll
    for (int mt = 0; mt < 2; ++mt)
#pragma unroll
        for (int jt = 0; jt < 2; ++jt)
#pragma unroll
            for (int rg = 0; rg < 4; ++rg) {
                int a = 16 * mt + hi4 + rg;
                int j = 32 * wvi + 16 * jt + cx;
                creg[mt][jt][rg] = c0[(bk * 32 + a) * 128 + j];
            }
    __syncthreads();

    // ---------------- 30-step recurrence ----------------
#pragma unroll 1
    for (int t = 0; t < 30; ++t) {
        // wait for producer blocks: one producer flag per lane of wave 0,
        // divergent spin == "until all satisfied" via exec mask. Producer of
        // 64-elem chunk g (global) is block (g&255) at step (g>>8).
        if (wvi == 0) {
            int W0w = 16384 * t + 1280 * bk;
            int Wend = W0w + 1280;
            if (Wend > 327680) {
                int q0 = (W0w > 327680) ? (W0w - 327680) : 0;
                int g = (q0 >> 6) + lane;
                int gend = (Wend - 327681) >> 6;
                if (g <= gend) {
                    int s = g >> 8, P = g & 255;
                    while (__hip_atomic_load(&flags[P], __ATOMIC_RELAXED, __HIP_MEMORY_SCOPE_AGENT) <= s)
                        __builtin_amdgcn_s_sleep(1);
                }
                __threadfence();  // acquire: order window loads after flag observations
            }
        }
        __syncthreads();  // B1

        // stage window (stream = traj_rel ++ dout), f32 stats partials
        int W0 = 16384 * t + 1280 * bk;
        {
            int p = W0 + 4 * tid;
            const float* src = (p < 327680) ? (traj_rel + p) : (dout + (p - 327680));
            f4 v = *(const f4*)src;
            int a = tid / 10, kq = (tid % 10) * 4;
            u32 lo = (u32)f2bf(v[0]) | ((u32)f2bf(v[1]) << 16);
            u32 hh = (u32)f2bf(v[2]) | ((u32)f2bf(v[3]) << 16);
            u32* dst = (u32*)(s_win + ((kq >> 3) * 32 + a) * 8 + (kq & 7));
            dst[0] = lo; dst[1] = hh;
            s_wp[tid] = f2{v[0] + v[1] + v[2] + v[3],
                           v[0] * v[0] + v[1] * v[1] + v[2] * v[2] + v[3] * v[3]};
        }
        if (tid < 64) {
            int idx1 = tid + 256;
            int p = W0 + 4 * idx1;
            const float* src = (p < 327680) ? (traj_rel + p) : (dout + (p - 327680));
            f4 v = *(const f4*)src;
            int a = idx1 / 10, kq = (idx1 % 10) * 4;
            u32 lo = (u32)f2bf(v[0]) | ((u32)f2bf(v[1]) << 16);
            u32 hh = (u32)f2bf(v[2]) | ((u32)f2bf(v[3]) << 16);
            u32* dst = (u32*)(s_win + ((kq >> 3) * 32 + a) * 8 + (kq & 7));
            dst[0] = lo; dst[1] = hh;
            s_wp[idx1] = f2{v[0] + v[1] + v[2] + v[3],
                            v[0] * v[0] + v[1] * v[1] + v[2] * v[2] + v[3] * v[3]};
        }
        __syncthreads();  // B2: window + partials ready

        // ln1 stats (deterministic serial sum per agent)
        if (tid < 32) {
            float s = 0.f, s2 = 0.f;
#pragma unroll
            for (int u = 0; u < 10; ++u) {
                f2 p = s_wp[tid * 10 + u];
                s += p[0]; s2 += p[1];
            }
            float m = s * (1.0f / 40.0f);
            float var = s2 * (1.0f / 40.0f) - m * m;
            s_mr[tid][0] = m;
            s_mr[tid][1] = __builtin_amdgcn_rsqf(var + 1e-5f);
        }
        // embedding MFMA on raw bf16 window
        f4 accE[2];
        accE[0] = f4{0.f, 0.f, 0.f, 0.f};
        accE[1] = f4{0.f, 0.f, 0.f, 0.f};
#pragma unroll
        for (int kc = 0; kc < 2; ++kc)
#pragma unroll
            for (int mt = 0; mt < 2; ++mt) {
                s8v a = *(const s8v*)(s_win + ((kc * 4 + (lane >> 4)) * 32 + 16 * mt + cx) * 8);
                accE[mt] = __builtin_amdgcn_mfma_f32_16x16x32_bf16(a, wgf[kc], accE[mt], 0, 0, 0);
            }
        __syncthreads();  // B3: s_mr ready

        // emb epilogue: ln1 fold + leaky_relu -> xh (bf16)
        {
            int e = 16 * wvi + cx;
#pragma unroll
            for (int mt = 0; mt < 2; ++mt)
#pragma unroll
                for (int rg = 0; rg < 4; ++rg) {
                    int a = 16 * mt + hi4 + rg;
                    float m = s_mr[a][0], r = s_mr[a][1];
                    float x = r * (accE[mt][rg] - m * se_l) + te_l;
                    x = fmaxf(x, 0.f) + 0.01f * fminf(x, 0.f);
                    s_xh[((e >> 3) * 32 + a) * 8 + (e & 7)] = f2bf(x);
                }
        }
        __syncthreads();  // B4: xh (x new, h from prev step) complete

        // gates GEMM [32 x 192] x [192 x 512]
        f4 acc[2][8];
#pragma unroll
        for (int mt = 0; mt < 2; ++mt)
#pragma unroll
            for (int nt = 0; nt < 8; ++nt)
                acc[mt][nt] = f4{bias[nt], bias[nt], bias[nt], bias[nt]};
#pragma unroll
        for (int kc = 0; kc < 6; ++kc) {
            s8v a0 = *(const s8v*)(s_xh + ((kc * 4 + (lane >> 4)) * 32 + cx) * 8);
            s8v a1 = *(const s8v*)(s_xh + ((kc * 4 + (lane >> 4)) * 32 + 16 + cx) * 8);
#pragma unroll
            for (int nt = 0; nt < 8; ++nt) {
                s8v b;
                if (kc < 2) b = wih[nt][kc];
                else b = *(const s8v*)(s_whh + (((kc - 2) * 4 + (lane >> 4)) * 512 + 128 * wvi + 16 * nt + cx) * 8);
                acc[0][nt] = __builtin_amdgcn_mfma_f32_16x16x32_bf16(a0, b, acc[0][nt], 0, 0, 0);
                acc[1][nt] = __builtin_amdgcn_mfma_f32_16x16x32_bf16(a1, b, acc[1][nt], 0, 0, 0);
            }
        }
        __syncthreads();  // B5: all old-h reads done before overwrite

        // LSTM pointwise (all in-register; gate rows pre-permuted)
        float sh[2][4], sh2[2][4], sp0[2][4], sp1[2][4];
#pragma unroll
        for (int mt = 0; mt < 2; ++mt)
#pragma unroll
            for (int rg = 0; rg < 4; ++rg) {
                sh[mt][rg] = 0.f; sh2[mt][rg] = 0.f; sp0[mt][rg] = 0.f; sp1[mt][rg] = 0.f;
            }
#pragma unroll
        for (int mt = 0; mt < 2; ++mt)
#pragma unroll
            for (int jt = 0; jt < 2; ++jt)
#pragma unroll
                for (int rg = 0; rg < 4; ++rg) {
                    float iv = acc[mt][jt][rg];
                    float fv = acc[mt][2 + jt][rg];
                    float gv = acc[mt][4 + jt][rg];
                    float ov = acc[mt][6 + jt][rg];
                    float si = __builtin_amdgcn_rcpf(1.f + __builtin_amdgcn_exp2f(-K1 * iv));
                    float sf = __builtin_amdgcn_rcpf(1.f + __builtin_amdgcn_exp2f(-K1 * fv));
                    float so = __builtin_amdgcn_rcpf(1.f + __builtin_amdgcn_exp2f(-K1 * ov));
                    float tg = 1.f - 2.f * __builtin_amdgcn_rcpf(1.f + __builtin_amdgcn_exp2f(K2 * gv));
                    float cn = sf * creg[mt][jt][rg] + si * tg;
                    creg[mt][jt][rg] = cn;
                    float tc = 1.f - 2.f * __builtin_amdgcn_rcpf(1.f + __builtin_amdgcn_exp2f(K2 * cn));
                    float hn = so * tc;
                    sh[mt][rg] += hn;
                    sh2[mt][rg] += hn * hn;
                    sp0[mt][rg] += hn * pwl[0][jt];
                    sp1[mt][rg] += hn * pwl[1][jt];
                    int k = 64 + 32 * wvi + 16 * jt + cx;
                    int a = 16 * mt + hi4 + rg;
                    s_xh[((k >> 3) * 32 + a) * 8 + (k & 7)] = f2bf(hn);
                }
        // reduce ln2 partial sums across the 16-lane column group
#pragma unroll
        for (int mt = 0; mt < 2; ++mt)
#pragma unroll
            for (int rg = 0; rg < 4; ++rg) {
                float a0 = sh[mt][rg], a1 = sh2[mt][rg], a2 = sp0[mt][rg], a3 = sp1[mt][rg];
#pragma unroll
                for (int m = 1; m < 16; m <<= 1) {
                    a0 += __shfl_xor(a0, m, 64);
                    a1 += __shfl_xor(a1, m, 64);
                    a2 += __shfl_xor(a2, m, 64);
                    a3 += __shfl_xor(a3, m, 64);
                }
                if (cx == 0) {
                    int a = 16 * mt + hi4 + rg;
                    s_red[wvi][a][0] = a0; s_red[wvi][a][1] = a1;
                    s_red[wvi][a][2] = a2; s_red[wvi][a][3] = a3;
                }
            }
        __syncthreads();  // B6: partials ready (and new h written)

        // combine: ln2 fold -> rel_pos -> d_out (the shared stream)
        if (tid < 64) {
            int a = tid & 31, d = tid >> 5;
            f4 s0 = *(f4*)&s_red[0][a][0];
            f4 s1 = *(f4*)&s_red[1][a][0];
            f4 s2 = *(f4*)&s_red[2][a][0];
            f4 s3 = *(f4*)&s_red[3][a][0];
            f4 sum = s0 + s1 + s2 + s3;
            float m = sum[0] * (1.f / 128.f);
            float var = sum[1] * (1.f / 128.f) - m * m;
            float r = __builtin_amdgcn_rsqf(var + 1e-5f);
            float P = (d == 0) ? sum[2] : sum[3];
            float sp = (d == 0) ? spw0 : spw1;
            float pb = (d == 0) ? pbe0 : pbe1;
            dout[(t * 8192 + bk * 32 + a) * 2 + d] = r * (P - m * sp) + pb;
        }
        __syncthreads();  // B7: pred stores drained (waitcnt before barrier)
        if (tid == 0)
            __hip_atomic_store(&flags[bk], t + 1, __ATOMIC_RELEASE, __HIP_MEMORY_SCOPE_AGENT);
    }
}

extern "C" void kernel_launch(void* const* d_in, const int* in_sizes, int n_in,
                              void* d_out, int out_size, void* d_ws, size_t ws_size,
                              hipStream_t stream) {
    (void)in_sizes; (void)n_in; (void)out_size; (void)ws_size;
    const float* traj_rel = (const float*)d_in[1];
    const float* h0 = (const float*)d_in[2];
    const float* c0 = (const float*)d_in[3];
    const float* ln1w = (const float*)d_in[4];
    const float* ln1b = (const float*)d_in[5];
    const float* embW = (const float*)d_in[6];
    const float* embB = (const float*)d_in[7];
    const float* Wih = (const float*)d_in[8];
    const float* Whh = (const float*)d_in[9];
    const float* bih = (const float*)d_in[10];
    const float* bhh = (const float*)d_in[11];
    const float* ln2w = (const float*)d_in[12];
    const float* ln2b = (const float*)d_in[13];
    const float* posW = (const float*)d_in[14];
    const float* posB = (const float*)d_in[15];
    char* ws = (char*)d_ws;

    hipLaunchKernelGGL(prep_kernel, dim3(1), dim3(256), 0, stream,
                       ln1w, ln1b, embW, embB, Wih, Whh, bih, bhh, ln2w, ln2b, posW, posB, ws);
    hipLaunchKernelGGL(lstm_kernel, dim3(256), dim3(256), 0, stream,
                       traj_rel, h0, c0, (float*)d_out, ws);
}